// Round 3
// baseline (611.610 us; speedup 1.0000x reference)
//
#include <hip/hip_runtime.h>

#define Nn 100000
#define Ee 1600000
#define HID 128
#define IN_DIM 5

// Native f32 atomic add (global_atomic_add_f32), no CAS loop.
__device__ __forceinline__ void fadd(float* p, float v) {
    unsafeAtomicAdd(p, v);
}

// ---------- kernel 1: in-degree (over dst) ----------
__global__ void deg_kernel(const int* __restrict__ dst, float* __restrict__ deg) {
    int e = blockIdx.x * blockDim.x + threadIdx.x;
    if (e < Ee) fadd(&deg[dst[e]], 1.0f);
}

// ---------- kernel 2: dinv = rsqrt(deg+1); xd[n][k] = x[n][k]*dinv[n] ----------
__global__ void prep_kernel(const float* __restrict__ x, float* __restrict__ deg_dinv,
                            float* __restrict__ xd) {
    int i = blockIdx.x * blockDim.x + threadIdx.x;
    if (i < Nn) {
        float di = rsqrtf(deg_dinv[i] + 1.0f);
        deg_dinv[i] = di;
        #pragma unroll
        for (int k = 0; k < IN_DIM; ++k)
            xd[i * IN_DIM + k] = x[i * IN_DIM + k] * di;
    }
}

// ---------- kernel 3: layer-1 INPUT-side aggregation (5 floats/edge) ----------
__global__ void scatter_x_kernel(const int* __restrict__ src, const int* __restrict__ dst,
                                 const float* __restrict__ xd, const float* __restrict__ dinv,
                                 float* __restrict__ pre1) {
    int e = blockIdx.x * blockDim.x + threadIdx.x;
    if (e < Ee) {
        int s = src[e], d = dst[e];
        float dd = dinv[d];
        #pragma unroll
        for (int k = 0; k < IN_DIM; ++k)
            fadd(&pre1[d * IN_DIM + k], xd[s * IN_DIM + k] * dd);
    }
}

// ---------- kernel 4: layer-1 finish + ReLU + layer-2 projection ----------
__global__ void node1_kernel(const float* __restrict__ pre1, const float* __restrict__ xd,
                             const float* __restrict__ W1, const float* __restrict__ b1,
                             const float* __restrict__ W2, const float* __restrict__ dinv,
                             float* __restrict__ h2d) {
    int n = blockIdx.x;
    int f = threadIdx.x;                    // 0..127
    float di = dinv[n];
    float a5[IN_DIM];
    #pragma unroll
    for (int k = 0; k < IN_DIM; ++k)
        a5[k] = pre1[n * IN_DIM + k] + xd[n * IN_DIM + k] * di;
    float v = b1[f];
    #pragma unroll
    for (int k = 0; k < IN_DIM; ++k)
        v += a5[k] * W1[k * HID + f];
    v = fmaxf(v, 0.f);                      // ReLU
    float p = v * W2[f];                    // 128 -> 1 projection
    #pragma unroll
    for (int off = 32; off; off >>= 1) p += __shfl_down(p, off, 64);
    __shared__ float ls[2];
    if ((f & 63) == 0) ls[f >> 6] = p;
    __syncthreads();
    if (f == 0) h2d[n] = (ls[0] + ls[1]) * di;
}

// ---------- kernel 5: layer-2 edge scatter (scalar) ----------
__global__ void scatter2_kernel(const int* __restrict__ src, const int* __restrict__ dst,
                                const float* __restrict__ h2d, const float* __restrict__ dinv,
                                float* __restrict__ out) {
    int e = blockIdx.x * blockDim.x + threadIdx.x;
    if (e < Ee) {
        int s = src[e], d = dst[e];
        fadd(&out[d], h2d[s] * dinv[d]);
    }
}

// ---------- kernel 6: layer-2 self-loop + b2 ----------
__global__ void final_kernel(const float* __restrict__ h2d, const float* __restrict__ dinv,
                             const float* __restrict__ b2, float* __restrict__ out) {
    int n = blockIdx.x * blockDim.x + threadIdx.x;
    if (n < Nn) out[n] += h2d[n] * dinv[n] + b2[0];
}

extern "C" void kernel_launch(void* const* d_in, const int* in_sizes, int n_in,
                              void* d_out, int out_size, void* d_ws, size_t ws_size,
                              hipStream_t stream) {
    const float* x  = (const float*)d_in[0];
    const int*   ei = (const int*)d_in[1];     // [2, E]: src row then dst row
    const float* W1 = (const float*)d_in[2];   // [5, 128] row-major
    const float* b1 = (const float*)d_in[3];   // [128]
    const float* W2 = (const float*)d_in[4];   // [128, 1]
    const float* b2 = (const float*)d_in[5];   // [1]
    const int* src = ei;
    const int* dst = ei + Ee;

    float* dinv = (float*)d_ws;                     // N   (deg -> dinv in place)
    float* xd   = dinv + Nn;                        // N*5
    float* pre1 = xd + (size_t)Nn * IN_DIM;         // N*5
    float* h2d  = pre1 + (size_t)Nn * IN_DIM;       // N
    float* out  = (float*)d_out;                    // N

    hipMemsetAsync(dinv, 0, (size_t)Nn * sizeof(float), stream);
    hipMemsetAsync(pre1, 0, (size_t)Nn * IN_DIM * sizeof(float), stream);
    hipMemsetAsync(out,  0, (size_t)Nn * sizeof(float), stream);

    deg_kernel<<<(Ee + 255) / 256, 256, 0, stream>>>(dst, dinv);
    prep_kernel<<<(Nn + 255) / 256, 256, 0, stream>>>(x, dinv, xd);
    scatter_x_kernel<<<(Ee + 255) / 256, 256, 0, stream>>>(src, dst, xd, dinv, pre1);
    node1_kernel<<<Nn, HID, 0, stream>>>(pre1, xd, W1, b1, W2, dinv, h2d);
    scatter2_kernel<<<(Ee + 255) / 256, 256, 0, stream>>>(src, dst, h2d, dinv, out);
    final_kernel<<<(Nn + 255) / 256, 256, 0, stream>>>(h2d, dinv, b2, out);
}

// Round 4
// 313.410 us; speedup vs baseline: 1.9515x; 1.9515x over previous
//
#include <hip/hip_runtime.h>

#define Nn 100000
#define Ee 1600000
#define HID 128
#define IN_DIM 5
#define N5 (Nn * IN_DIM)

// ---- binning geometry ----
// scalar passes (deg, layer-2): 8192 nodes/bucket (shift 13), 13 buckets, 20 edge-chunks
#define SH1 13
#define BSZ1 8192
#define NB1 13
#define BPB1 20
// layer-1 pre-agg (5 floats/node): 4096 nodes/bucket (shift 12), 25 buckets, 16 edge-chunks
#define SH2 12
#define BSZ2 4096
#define NB2 25
#define BPB2 16

// ---------- kernel 1: binned in-degree ----------
__global__ __launch_bounds__(512) void degbin_kernel(const int* __restrict__ dst,
                                                     float* __restrict__ degp) {
    __shared__ int acc[BSZ1];                       // 32 KB
    int b = blockIdx.x / BPB1, sub = blockIdx.x % BPB1;
    int base = b << SH1;
    int cnt = min(BSZ1, Nn - base);
    for (int i = threadIdx.x; i < BSZ1; i += 512) acc[i] = 0;
    __syncthreads();
    int e0 = sub * (Ee / BPB1);                     // 80000-edge chunk
    for (int e = e0 + threadIdx.x; e < e0 + Ee / BPB1; e += 512) {
        int d = dst[e];
        if ((d >> SH1) == b) atomicAdd(&acc[d - base], 1);
    }
    __syncthreads();
    float* o = degp + (size_t)sub * Nn + base;
    for (int i = threadIdx.x; i < cnt; i += 512) o[i] = (float)acc[i];
}

// ---------- kernel 2: dinv = rsqrt(sum(degp)+1); xd = x*dinv ----------
__global__ void prep_kernel(const float* __restrict__ x, const float* __restrict__ degp,
                            float* __restrict__ dinv, float* __restrict__ xd) {
    int i = blockIdx.x * blockDim.x + threadIdx.x;
    if (i < Nn) {
        float dg = 1.0f;
        for (int sub = 0; sub < BPB1; ++sub) dg += degp[(size_t)sub * Nn + i];  // coalesced
        float di = rsqrtf(dg);
        dinv[i] = di;
        #pragma unroll
        for (int k = 0; k < IN_DIM; ++k)
            xd[i * IN_DIM + k] = x[i * IN_DIM + k] * di;
    }
}

// ---------- kernel 3: binned layer-1 input aggregation ----------
// acc[d_local] += xd[src]  (dinv[d] applied later, once per node)
__global__ __launch_bounds__(512) void pre1bin_kernel(const int* __restrict__ src,
                                                      const int* __restrict__ dst,
                                                      const float* __restrict__ xd,
                                                      float* __restrict__ pre1p) {
    __shared__ float acc[BSZ2 * IN_DIM];            // 80 KB -> 2 blocks/CU
    int b = blockIdx.x / BPB2, sub = blockIdx.x % BPB2;
    int base = b << SH2;
    int cnt = min(BSZ2, Nn - base);
    for (int i = threadIdx.x; i < BSZ2 * IN_DIM; i += 512) acc[i] = 0.f;
    __syncthreads();
    int e0 = sub * (Ee / BPB2);                     // 100000-edge chunk
    for (int e = e0 + threadIdx.x; e < e0 + Ee / BPB2; e += 512) {
        int d = dst[e];
        if ((d >> SH2) == b) {
            int s = src[e];
            int dl = (d - base) * IN_DIM;
            #pragma unroll
            for (int k = 0; k < IN_DIM; ++k)
                atomicAdd(&acc[dl + k], xd[s * IN_DIM + k]);
        }
    }
    __syncthreads();
    float* o = pre1p + (size_t)sub * N5 + (size_t)base * IN_DIM;
    for (int i = threadIdx.x; i < cnt * IN_DIM; i += 512) o[i] = acc[i];
}

// ---------- kernel 4: reduce partials, apply dinv[d] ----------
__global__ void reduce_pre1_kernel(const float* __restrict__ pre1p,
                                   const float* __restrict__ dinv, float* __restrict__ pre1) {
    int j = blockIdx.x * blockDim.x + threadIdx.x;
    if (j < N5) {
        float v = 0.f;
        for (int sub = 0; sub < BPB2; ++sub) v += pre1p[(size_t)sub * N5 + j];  // coalesced
        pre1[j] = v * dinv[j / IN_DIM];
    }
}

// ---------- kernel 5: layer-1 finish + ReLU + layer-2 projection ----------
__global__ void node1_kernel(const float* __restrict__ pre1, const float* __restrict__ xd,
                             const float* __restrict__ W1, const float* __restrict__ b1,
                             const float* __restrict__ W2, const float* __restrict__ dinv,
                             float* __restrict__ h2d) {
    int n = blockIdx.x;
    int f = threadIdx.x;                    // 0..127
    float di = dinv[n];
    float a5[IN_DIM];
    #pragma unroll
    for (int k = 0; k < IN_DIM; ++k)
        a5[k] = pre1[n * IN_DIM + k] + xd[n * IN_DIM + k] * di;
    float v = b1[f];
    #pragma unroll
    for (int k = 0; k < IN_DIM; ++k)
        v += a5[k] * W1[k * HID + f];
    v = fmaxf(v, 0.f);                      // ReLU
    float p = v * W2[f];                    // 128 -> 1 projection
    #pragma unroll
    for (int off = 32; off; off >>= 1) p += __shfl_down(p, off, 64);
    __shared__ float ls[2];
    if ((f & 63) == 0) ls[f >> 6] = p;
    __syncthreads();
    if (f == 0) h2d[n] = (ls[0] + ls[1]) * di;
}

// ---------- kernel 6: binned layer-2 scatter (scalar) ----------
__global__ __launch_bounds__(512) void out2bin_kernel(const int* __restrict__ src,
                                                      const int* __restrict__ dst,
                                                      const float* __restrict__ h2d,
                                                      float* __restrict__ outp) {
    __shared__ float acc[BSZ1];                     // 32 KB
    int b = blockIdx.x / BPB1, sub = blockIdx.x % BPB1;
    int base = b << SH1;
    int cnt = min(BSZ1, Nn - base);
    for (int i = threadIdx.x; i < BSZ1; i += 512) acc[i] = 0.f;
    __syncthreads();
    int e0 = sub * (Ee / BPB1);
    for (int e = e0 + threadIdx.x; e < e0 + Ee / BPB1; e += 512) {
        int d = dst[e];
        if ((d >> SH1) == b) atomicAdd(&acc[d - base], h2d[src[e]]);
    }
    __syncthreads();
    float* o = outp + (size_t)sub * Nn + base;
    for (int i = threadIdx.x; i < cnt; i += 512) o[i] = acc[i];
}

// ---------- kernel 7: final reduce + self-loop + b2 ----------
__global__ void final_kernel(const float* __restrict__ outp, const float* __restrict__ h2d,
                             const float* __restrict__ dinv, const float* __restrict__ b2,
                             float* __restrict__ out) {
    int n = blockIdx.x * blockDim.x + threadIdx.x;
    if (n < Nn) {
        float v = 0.f;
        for (int sub = 0; sub < BPB1; ++sub) v += outp[(size_t)sub * Nn + n];   // coalesced
        out[n] = (v + h2d[n]) * dinv[n] + b2[0];
    }
}

extern "C" void kernel_launch(void* const* d_in, const int* in_sizes, int n_in,
                              void* d_out, int out_size, void* d_ws, size_t ws_size,
                              hipStream_t stream) {
    const float* x  = (const float*)d_in[0];
    const int*   ei = (const int*)d_in[1];     // [2, E]: src row then dst row
    const float* W1 = (const float*)d_in[2];
    const float* b1 = (const float*)d_in[3];
    const float* W2 = (const float*)d_in[4];
    const float* b2 = (const float*)d_in[5];
    const int* src = ei;
    const int* dst = ei + Ee;

    float* dinv  = (float*)d_ws;                    // N
    float* xd    = dinv + Nn;                       // N*5
    float* h2d   = xd + N5;                         // N
    float* pre1  = h2d + Nn;                        // N*5
    float* degp  = pre1 + N5;                       // BPB1*N  (reused as outp)
    float* pre1p = degp + (size_t)BPB1 * Nn;        // BPB2*N5 (32 MB)
    float* outp  = degp;                            // alias: deg consumed before layer 2
    float* out   = (float*)d_out;

    degbin_kernel<<<NB1 * BPB1, 512, 0, stream>>>(dst, degp);
    prep_kernel<<<(Nn + 255) / 256, 256, 0, stream>>>(x, degp, dinv, xd);
    pre1bin_kernel<<<NB2 * BPB2, 512, 0, stream>>>(src, dst, xd, pre1p);
    reduce_pre1_kernel<<<(N5 + 255) / 256, 256, 0, stream>>>(pre1p, dinv, pre1);
    node1_kernel<<<Nn, HID, 0, stream>>>(pre1, xd, W1, b1, W2, dinv, h2d);
    out2bin_kernel<<<NB1 * BPB1, 512, 0, stream>>>(src, dst, h2d, outp);
    final_kernel<<<(Nn + 255) / 256, 256, 0, stream>>>(outp, h2d, dinv, b2, out);
}

// Round 5
// 159.090 us; speedup vs baseline: 3.8444x; 1.9700x over previous
//
#include <hip/hip_runtime.h>

#define Nn 100000
#define Ee 1600000
#define HID 128
#define IN_DIM 5
#define N5 (Nn * IN_DIM)

// ---- bucket geometry: 4096 nodes/bucket, 25 buckets ----
#define SH2 12
#define BSZ2 4096
#define NB2 25
#define BCAP 69632        // per-bucket record capacity (expect 65536, sigma ~250)

#define PCHUNK 4000       // edges per partition block
#define PBLK (Ee / PCHUNK)   // 400 blocks

#define CPB1 8            // chunks/bucket for scalar passes (deg, out2)
#define CPB2 12           // chunks/bucket for 5-float pass (pre1)

// ---------- kernel 1: one-pass radix partition of the edge list ----------
// rec = (d_local << 17) | src   (src < 2^17, d_local < 2^12)
__global__ __launch_bounds__(512) void partition_kernel(const int* __restrict__ src,
                                                        const int* __restrict__ dst,
                                                        unsigned int* __restrict__ recs,
                                                        int* __restrict__ bcnt) {
    __shared__ unsigned int stage[PCHUNK];   // 16 KB, bucket-grouped records
    __shared__ int hist[NB2 + 1];            // exclusive-scan boundaries
    __shared__ int cur[NB2];                 // scatter cursors
    __shared__ int gbase[NB2];               // reserved global offsets
    int e0 = blockIdx.x * PCHUNK;
    if (threadIdx.x <= NB2) hist[threadIdx.x] = 0;
    __syncthreads();
    for (int e = e0 + threadIdx.x; e < e0 + PCHUNK; e += 512)
        atomicAdd(&hist[(dst[e] >> SH2) + 1], 1);
    __syncthreads();
    if (threadIdx.x == 0)
        for (int b = 1; b <= NB2; ++b) hist[b] += hist[b - 1];
    __syncthreads();
    if (threadIdx.x < NB2) {
        int c0 = hist[threadIdx.x], c1 = hist[threadIdx.x + 1];
        cur[threadIdx.x] = c0;
        gbase[threadIdx.x] = atomicAdd(&bcnt[threadIdx.x], c1 - c0);
    }
    __syncthreads();
    for (int e = e0 + threadIdx.x; e < e0 + PCHUNK; e += 512) {
        int d = dst[e], s = src[e];
        int b = d >> SH2;
        int slot = atomicAdd(&cur[b], 1);
        stage[slot] = ((unsigned int)(d & (BSZ2 - 1)) << 17) | (unsigned int)s;
    }
    __syncthreads();
    for (int b = 0; b < NB2; ++b) {
        int c0 = hist[b], len = hist[b + 1] - c0;
        unsigned int* o = recs + (size_t)b * BCAP + gbase[b];
        for (int i = threadIdx.x; i < len; i += 512) o[i] = stage[c0 + i];
    }
}

// ---------- kernel 2: per-bucket in-degree from records ----------
__global__ __launch_bounds__(512) void degbin2_kernel(const unsigned int* __restrict__ recs,
                                                      const int* __restrict__ bcnt,
                                                      float* __restrict__ degp) {
    __shared__ int acc[BSZ2];                // 16 KB
    int b = blockIdx.x / CPB1, c = blockIdx.x % CPB1;
    int n = bcnt[b];
    int r0 = (int)((long long)n * c / CPB1), r1 = (int)((long long)n * (c + 1) / CPB1);
    for (int i = threadIdx.x; i < BSZ2; i += 512) acc[i] = 0;
    __syncthreads();
    const unsigned int* R = recs + (size_t)b * BCAP;
    for (int i = r0 + threadIdx.x; i < r1; i += 512)
        atomicAdd(&acc[R[i] >> 17], 1);
    __syncthreads();
    int base = b << SH2;
    int cnt = min(BSZ2, Nn - base);
    float* o = degp + (size_t)c * Nn + base;
    for (int i = threadIdx.x; i < cnt; i += 512) o[i] = (float)acc[i];
}

// ---------- kernel 3: dinv = rsqrt(deg+1); xd = x*dinv ----------
__global__ void prep_kernel(const float* __restrict__ x, const float* __restrict__ degp,
                            float* __restrict__ dinv, float* __restrict__ xd) {
    int i = blockIdx.x * blockDim.x + threadIdx.x;
    if (i < Nn) {
        float dg = 1.0f;
        #pragma unroll
        for (int c = 0; c < CPB1; ++c) dg += degp[(size_t)c * Nn + i];
        float di = rsqrtf(dg);
        dinv[i] = di;
        #pragma unroll
        for (int k = 0; k < IN_DIM; ++k)
            xd[i * IN_DIM + k] = x[i * IN_DIM + k] * di;
    }
}

// ---------- kernel 4: layer-1 input aggregation from records ----------
__global__ __launch_bounds__(512) void pre1bin2_kernel(const unsigned int* __restrict__ recs,
                                                       const int* __restrict__ bcnt,
                                                       const float* __restrict__ xd,
                                                       float* __restrict__ pre1p) {
    __shared__ float acc[BSZ2 * IN_DIM];     // 80 KB
    int b = blockIdx.x / CPB2, c = blockIdx.x % CPB2;
    int n = bcnt[b];
    int r0 = (int)((long long)n * c / CPB2), r1 = (int)((long long)n * (c + 1) / CPB2);
    for (int i = threadIdx.x; i < BSZ2 * IN_DIM; i += 512) acc[i] = 0.f;
    __syncthreads();
    const unsigned int* R = recs + (size_t)b * BCAP;
    for (int i = r0 + threadIdx.x; i < r1; i += 512) {
        unsigned int r = R[i];
        int s = (int)(r & 0x1FFFFu);
        int dl = (int)(r >> 17) * IN_DIM;
        #pragma unroll
        for (int k = 0; k < IN_DIM; ++k)
            atomicAdd(&acc[dl + k], xd[s * IN_DIM + k]);
    }
    __syncthreads();
    int base = b << SH2;
    int cnt = min(BSZ2, Nn - base) * IN_DIM;
    float* o = pre1p + (size_t)c * N5 + (size_t)base * IN_DIM;
    for (int i = threadIdx.x; i < cnt; i += 512) o[i] = acc[i];
}

// ---------- kernel 5: reduce pre1 partials, apply dinv[d] ----------
__global__ void reduce_pre1_kernel(const float* __restrict__ pre1p,
                                   const float* __restrict__ dinv, float* __restrict__ pre1) {
    int j = blockIdx.x * blockDim.x + threadIdx.x;
    if (j < N5) {
        float v = 0.f;
        #pragma unroll
        for (int c = 0; c < CPB2; ++c) v += pre1p[(size_t)c * N5 + j];
        pre1[j] = v * dinv[j / IN_DIM];
    }
}

// ---------- kernel 6: layer-1 finish + ReLU + layer-2 projection ----------
__global__ void node1_kernel(const float* __restrict__ pre1, const float* __restrict__ xd,
                             const float* __restrict__ W1, const float* __restrict__ b1,
                             const float* __restrict__ W2, const float* __restrict__ dinv,
                             float* __restrict__ h2d) {
    int n = blockIdx.x;
    int f = threadIdx.x;                    // 0..127
    float di = dinv[n];
    float a5[IN_DIM];
    #pragma unroll
    for (int k = 0; k < IN_DIM; ++k)
        a5[k] = pre1[n * IN_DIM + k] + xd[n * IN_DIM + k] * di;
    float v = b1[f];
    #pragma unroll
    for (int k = 0; k < IN_DIM; ++k)
        v += a5[k] * W1[k * HID + f];
    v = fmaxf(v, 0.f);                      // ReLU
    float p = v * W2[f];                    // 128 -> 1 projection
    #pragma unroll
    for (int off = 32; off; off >>= 1) p += __shfl_down(p, off, 64);
    __shared__ float ls[2];
    if ((f & 63) == 0) ls[f >> 6] = p;
    __syncthreads();
    if (f == 0) h2d[n] = (ls[0] + ls[1]) * di;
}

// ---------- kernel 7: layer-2 scalar aggregation from records ----------
__global__ __launch_bounds__(512) void out2bin2_kernel(const unsigned int* __restrict__ recs,
                                                       const int* __restrict__ bcnt,
                                                       const float* __restrict__ h2d,
                                                       float* __restrict__ outp) {
    __shared__ float acc[BSZ2];              // 16 KB
    int b = blockIdx.x / CPB1, c = blockIdx.x % CPB1;
    int n = bcnt[b];
    int r0 = (int)((long long)n * c / CPB1), r1 = (int)((long long)n * (c + 1) / CPB1);
    for (int i = threadIdx.x; i < BSZ2; i += 512) acc[i] = 0.f;
    __syncthreads();
    const unsigned int* R = recs + (size_t)b * BCAP;
    for (int i = r0 + threadIdx.x; i < r1; i += 512) {
        unsigned int r = R[i];
        atomicAdd(&acc[r >> 17], h2d[r & 0x1FFFFu]);
    }
    __syncthreads();
    int base = b << SH2;
    int cnt = min(BSZ2, Nn - base);
    float* o = outp + (size_t)c * Nn + base;
    for (int i = threadIdx.x; i < cnt; i += 512) o[i] = acc[i];
}

// ---------- kernel 8: final reduce + self-loop + b2 ----------
__global__ void final_kernel(const float* __restrict__ outp, const float* __restrict__ h2d,
                             const float* __restrict__ dinv, const float* __restrict__ b2,
                             float* __restrict__ out) {
    int n = blockIdx.x * blockDim.x + threadIdx.x;
    if (n < Nn) {
        float v = 0.f;
        #pragma unroll
        for (int c = 0; c < CPB1; ++c) v += outp[(size_t)c * Nn + n];
        out[n] = (v + h2d[n]) * dinv[n] + b2[0];
    }
}

extern "C" void kernel_launch(void* const* d_in, const int* in_sizes, int n_in,
                              void* d_out, int out_size, void* d_ws, size_t ws_size,
                              hipStream_t stream) {
    const float* x  = (const float*)d_in[0];
    const int*   ei = (const int*)d_in[1];     // [2, E]: src row then dst row
    const float* W1 = (const float*)d_in[2];
    const float* b1 = (const float*)d_in[3];
    const float* W2 = (const float*)d_in[4];
    const float* b2 = (const float*)d_in[5];
    const int* src = ei;
    const int* dst = ei + Ee;

    float* dinv  = (float*)d_ws;                    // N
    float* xd    = dinv + Nn;                       // N*5
    float* h2d   = xd + N5;                         // N
    float* pre1  = h2d + Nn;                        // N*5
    float* degp  = pre1 + N5;                       // CPB1*N   (reused as outp)
    float* pre1p = degp + (size_t)CPB1 * Nn;        // CPB2*N5  (24 MB)
    unsigned int* recs = (unsigned int*)(pre1p + (size_t)CPB2 * N5);  // NB2*BCAP
    int* bcnt = (int*)(recs + (size_t)NB2 * BCAP);  // NB2 ints
    float* outp = degp;                             // alias: deg consumed before layer 2
    float* out  = (float*)d_out;

    hipMemsetAsync(bcnt, 0, NB2 * sizeof(int), stream);

    partition_kernel<<<PBLK, 512, 0, stream>>>(src, dst, recs, bcnt);
    degbin2_kernel<<<NB2 * CPB1, 512, 0, stream>>>(recs, bcnt, degp);
    prep_kernel<<<(Nn + 255) / 256, 256, 0, stream>>>(x, degp, dinv, xd);
    pre1bin2_kernel<<<NB2 * CPB2, 512, 0, stream>>>(recs, bcnt, xd, pre1p);
    reduce_pre1_kernel<<<(N5 + 255) / 256, 256, 0, stream>>>(pre1p, dinv, pre1);
    node1_kernel<<<Nn, HID, 0, stream>>>(pre1, xd, W1, b1, W2, dinv, h2d);
    out2bin2_kernel<<<NB2 * CPB1, 512, 0, stream>>>(recs, bcnt, h2d, outp);
    final_kernel<<<(Nn + 255) / 256, 256, 0, stream>>>(outp, h2d, dinv, b2, out);
}

// Round 6
// 147.944 us; speedup vs baseline: 4.1340x; 1.0753x over previous
//
#include <hip/hip_runtime.h>

#define Nn 100000
#define Ee 1600000
#define HID 128
#define IN_DIM 5
#define N5 (Nn * IN_DIM)

// ---- bucket geometry: 2048 nodes/bucket, 49 buckets ----
#define SH2 11
#define BSZ2 2048
#define NB2 49
#define BCAP 36864        // per-bucket record capacity (expect ~32653, sigma ~181)

#define PCHUNK 4000       // edges per partition block
#define PBLK (Ee / PCHUNK)   // 400 blocks

#define CPB1 8            // chunks/bucket for scalar passes (deg, out2)
#define CPB2 12           // chunks/bucket for 5-float pass (pre1)

// ---------- kernel 1: one-pass radix partition of the edge list ----------
// rec = (d_local << 17) | src   (src < 2^17, d_local < 2^11)
__global__ __launch_bounds__(512) void partition_kernel(const int* __restrict__ src,
                                                        const int* __restrict__ dst,
                                                        unsigned int* __restrict__ recs,
                                                        int* __restrict__ bcnt) {
    __shared__ unsigned int stage[PCHUNK];   // 16 KB, bucket-grouped records
    __shared__ int hist[NB2 + 1];
    __shared__ int cur[NB2];
    __shared__ int gbase[NB2];
    int e0 = blockIdx.x * PCHUNK;
    if (threadIdx.x <= NB2) hist[threadIdx.x] = 0;
    __syncthreads();
    for (int e = e0 + threadIdx.x; e < e0 + PCHUNK; e += 512)
        atomicAdd(&hist[(dst[e] >> SH2) + 1], 1);
    __syncthreads();
    if (threadIdx.x == 0)
        for (int b = 1; b <= NB2; ++b) hist[b] += hist[b - 1];
    __syncthreads();
    if (threadIdx.x < NB2) {
        int c0 = hist[threadIdx.x], c1 = hist[threadIdx.x + 1];
        cur[threadIdx.x] = c0;
        gbase[threadIdx.x] = atomicAdd(&bcnt[threadIdx.x], c1 - c0);
    }
    __syncthreads();
    for (int e = e0 + threadIdx.x; e < e0 + PCHUNK; e += 512) {
        int d = dst[e], s = src[e];
        int b = d >> SH2;
        int slot = atomicAdd(&cur[b], 1);
        stage[slot] = ((unsigned int)(d & (BSZ2 - 1)) << 17) | (unsigned int)s;
    }
    __syncthreads();
    for (int b = 0; b < NB2; ++b) {
        int c0 = hist[b], len = hist[b + 1] - c0;
        unsigned int* o = recs + (size_t)b * BCAP + gbase[b];
        for (int i = threadIdx.x; i < len; i += 512) o[i] = stage[c0 + i];
    }
}

// ---------- kernel 2: per-bucket in-degree from records ----------
__global__ __launch_bounds__(512) void degbin2_kernel(const unsigned int* __restrict__ recs,
                                                      const int* __restrict__ bcnt,
                                                      float* __restrict__ degp) {
    __shared__ int acc[BSZ2];                // 8 KB
    int b = blockIdx.x / CPB1, c = blockIdx.x % CPB1;
    int n = bcnt[b];
    int r0 = (int)((long long)n * c / CPB1), r1 = (int)((long long)n * (c + 1) / CPB1);
    for (int i = threadIdx.x; i < BSZ2; i += 512) acc[i] = 0;
    __syncthreads();
    const unsigned int* R = recs + (size_t)b * BCAP;
    for (int i = r0 + threadIdx.x; i < r1; i += 512)
        atomicAdd(&acc[R[i] >> 17], 1);
    __syncthreads();
    int base = b << SH2;
    int cnt = min(BSZ2, Nn - base);
    float* o = degp + (size_t)c * Nn + base;
    for (int i = threadIdx.x; i < cnt; i += 512) o[i] = (float)acc[i];
}

// ---------- kernel 3: dinv = rsqrt(deg+1); xd8 = x*dinv (8-float padded rows) ----------
__global__ void prep_kernel(const float* __restrict__ x, const float* __restrict__ degp,
                            float* __restrict__ dinv, float* __restrict__ xd8) {
    int i = blockIdx.x * blockDim.x + threadIdx.x;
    if (i < Nn) {
        float dg = 1.0f;
        #pragma unroll
        for (int c = 0; c < CPB1; ++c) dg += degp[(size_t)c * Nn + i];
        float di = rsqrtf(dg);
        dinv[i] = di;
        #pragma unroll
        for (int k = 0; k < IN_DIM; ++k)
            xd8[(size_t)i * 8 + k] = x[i * IN_DIM + k] * di;
    }
}

// ---------- kernel 4: layer-1 input aggregation from records (ILP-2) ----------
__global__ __launch_bounds__(512) void pre1bin2_kernel(const unsigned int* __restrict__ recs,
                                                       const int* __restrict__ bcnt,
                                                       const float* __restrict__ xd8,
                                                       float* __restrict__ pre1p) {
    __shared__ float acc[BSZ2 * IN_DIM];     // 40 KB -> 4 blocks/CU by LDS
    int b = blockIdx.x / CPB2, c = blockIdx.x % CPB2;
    int n = bcnt[b];
    int r0 = (int)((long long)n * c / CPB2), r1 = (int)((long long)n * (c + 1) / CPB2);
    float4* accv = (float4*)acc;
    for (int i = threadIdx.x; i < BSZ2 * IN_DIM / 4; i += 512)
        accv[i] = make_float4(0.f, 0.f, 0.f, 0.f);
    __syncthreads();
    const unsigned int* R = recs + (size_t)b * BCAP;
    int i = r0 + (int)threadIdx.x;
    for (; i + 512 < r1; i += 1024) {
        unsigned int ra = R[i], rb = R[i + 512];
        int sa = (int)(ra & 0x1FFFFu), sb = (int)(rb & 0x1FFFFu);
        float4 va = *(const float4*)&xd8[(size_t)sa * 8];
        float  wa = xd8[(size_t)sa * 8 + 4];
        float4 vb = *(const float4*)&xd8[(size_t)sb * 8];
        float  wb = xd8[(size_t)sb * 8 + 4];
        int da = (int)(ra >> 17) * IN_DIM, db = (int)(rb >> 17) * IN_DIM;
        atomicAdd(&acc[da + 0], va.x);
        atomicAdd(&acc[da + 1], va.y);
        atomicAdd(&acc[da + 2], va.z);
        atomicAdd(&acc[da + 3], va.w);
        atomicAdd(&acc[da + 4], wa);
        atomicAdd(&acc[db + 0], vb.x);
        atomicAdd(&acc[db + 1], vb.y);
        atomicAdd(&acc[db + 2], vb.z);
        atomicAdd(&acc[db + 3], vb.w);
        atomicAdd(&acc[db + 4], wb);
    }
    if (i < r1) {
        unsigned int ra = R[i];
        int sa = (int)(ra & 0x1FFFFu);
        float4 va = *(const float4*)&xd8[(size_t)sa * 8];
        float  wa = xd8[(size_t)sa * 8 + 4];
        int da = (int)(ra >> 17) * IN_DIM;
        atomicAdd(&acc[da + 0], va.x);
        atomicAdd(&acc[da + 1], va.y);
        atomicAdd(&acc[da + 2], va.z);
        atomicAdd(&acc[da + 3], va.w);
        atomicAdd(&acc[da + 4], wa);
    }
    __syncthreads();
    int base = b << SH2;
    int cnt4 = min(BSZ2, Nn - base) * IN_DIM / 4;   // always divisible by 4
    float4* o = (float4*)(pre1p + (size_t)c * N5 + (size_t)base * IN_DIM);
    for (int j = threadIdx.x; j < cnt4; j += 512) o[j] = accv[j];
}

// ---------- kernel 5: reduce pre1 partials, apply dinv[d] ----------
__global__ void reduce_pre1_kernel(const float* __restrict__ pre1p,
                                   const float* __restrict__ dinv, float* __restrict__ pre1) {
    int j = blockIdx.x * blockDim.x + threadIdx.x;
    if (j < N5) {
        float v = 0.f;
        #pragma unroll
        for (int c = 0; c < CPB2; ++c) v += pre1p[(size_t)c * N5 + j];
        pre1[j] = v * dinv[j / IN_DIM];
    }
}

// ---------- kernel 6: layer-1 finish + ReLU + layer-2 projection (2 nodes/block) ----------
__global__ __launch_bounds__(256) void node1_kernel(const float* __restrict__ pre1,
                             const float* __restrict__ xd8,
                             const float* __restrict__ W1, const float* __restrict__ b1,
                             const float* __restrict__ W2, const float* __restrict__ dinv,
                             float* __restrict__ h2d) {
    int tid = threadIdx.x;                  // 0..255
    int n = blockIdx.x * 2 + (tid >> 7);
    int f = tid & 127;
    float di = dinv[n];
    float a5[IN_DIM];
    #pragma unroll
    for (int k = 0; k < IN_DIM; ++k)
        a5[k] = pre1[n * IN_DIM + k] + xd8[(size_t)n * 8 + k] * di;
    float v = b1[f];
    #pragma unroll
    for (int k = 0; k < IN_DIM; ++k)
        v += a5[k] * W1[k * HID + f];
    v = fmaxf(v, 0.f);                      // ReLU
    float p = v * W2[f];                    // 128 -> 1 projection
    #pragma unroll
    for (int off = 32; off; off >>= 1) p += __shfl_down(p, off, 64);
    __shared__ float ls[4];
    if ((f & 63) == 0) ls[tid >> 6] = p;
    __syncthreads();
    if (f == 0) h2d[n] = (ls[(tid >> 6)] + ls[(tid >> 6) + 1]) * di;
}

// ---------- kernel 7: layer-2 scalar aggregation from records ----------
__global__ __launch_bounds__(512) void out2bin2_kernel(const unsigned int* __restrict__ recs,
                                                       const int* __restrict__ bcnt,
                                                       const float* __restrict__ h2d,
                                                       float* __restrict__ outp) {
    __shared__ float acc[BSZ2];              // 8 KB
    int b = blockIdx.x / CPB1, c = blockIdx.x % CPB1;
    int n = bcnt[b];
    int r0 = (int)((long long)n * c / CPB1), r1 = (int)((long long)n * (c + 1) / CPB1);
    for (int i = threadIdx.x; i < BSZ2; i += 512) acc[i] = 0.f;
    __syncthreads();
    const unsigned int* R = recs + (size_t)b * BCAP;
    int i = r0 + (int)threadIdx.x;
    for (; i + 512 < r1; i += 1024) {
        unsigned int ra = R[i], rb = R[i + 512];
        float ha = h2d[ra & 0x1FFFFu];
        float hb = h2d[rb & 0x1FFFFu];
        atomicAdd(&acc[ra >> 17], ha);
        atomicAdd(&acc[rb >> 17], hb);
    }
    if (i < r1) {
        unsigned int ra = R[i];
        atomicAdd(&acc[ra >> 17], h2d[ra & 0x1FFFFu]);
    }
    __syncthreads();
    int base = b << SH2;
    int cnt = min(BSZ2, Nn - base);
    float* o = outp + (size_t)c * Nn + base;
    for (int i2 = threadIdx.x; i2 < cnt; i2 += 512) o[i2] = acc[i2];
}

// ---------- kernel 8: final reduce + self-loop + b2 ----------
__global__ void final_kernel(const float* __restrict__ outp, const float* __restrict__ h2d,
                             const float* __restrict__ dinv, const float* __restrict__ b2,
                             float* __restrict__ out) {
    int n = blockIdx.x * blockDim.x + threadIdx.x;
    if (n < Nn) {
        float v = 0.f;
        #pragma unroll
        for (int c = 0; c < CPB1; ++c) v += outp[(size_t)c * Nn + n];
        out[n] = (v + h2d[n]) * dinv[n] + b2[0];
    }
}

extern "C" void kernel_launch(void* const* d_in, const int* in_sizes, int n_in,
                              void* d_out, int out_size, void* d_ws, size_t ws_size,
                              hipStream_t stream) {
    const float* x  = (const float*)d_in[0];
    const int*   ei = (const int*)d_in[1];     // [2, E]: src row then dst row
    const float* W1 = (const float*)d_in[2];
    const float* b1 = (const float*)d_in[3];
    const float* W2 = (const float*)d_in[4];
    const float* b2 = (const float*)d_in[5];
    const int* src = ei;
    const int* dst = ei + Ee;

    float* dinv  = (float*)d_ws;                    // N
    float* xd8   = dinv + Nn;                       // N*8 (padded rows, 16B-aligned)
    float* h2d   = xd8 + (size_t)Nn * 8;            // N
    float* pre1  = h2d + Nn;                        // N*5
    float* degp  = pre1 + N5;                       // CPB1*N   (reused as outp)
    float* pre1p = degp + (size_t)CPB1 * Nn;        // CPB2*N5  (24 MB)
    unsigned int* recs = (unsigned int*)(pre1p + (size_t)CPB2 * N5);  // NB2*BCAP
    int* bcnt = (int*)(recs + (size_t)NB2 * BCAP);  // NB2 ints
    float* outp = degp;                             // alias: deg consumed before layer 2
    float* out  = (float*)d_out;

    hipMemsetAsync(bcnt, 0, NB2 * sizeof(int), stream);

    partition_kernel<<<PBLK, 512, 0, stream>>>(src, dst, recs, bcnt);
    degbin2_kernel<<<NB2 * CPB1, 512, 0, stream>>>(recs, bcnt, degp);
    prep_kernel<<<(Nn + 255) / 256, 256, 0, stream>>>(x, degp, dinv, xd8);
    pre1bin2_kernel<<<NB2 * CPB2, 512, 0, stream>>>(recs, bcnt, xd8, pre1p);
    reduce_pre1_kernel<<<(N5 + 255) / 256, 256, 0, stream>>>(pre1p, dinv, pre1);
    node1_kernel<<<Nn / 2, 256, 0, stream>>>(pre1, xd8, W1, b1, W2, dinv, h2d);
    out2bin2_kernel<<<NB2 * CPB1, 512, 0, stream>>>(recs, bcnt, h2d, outp);
    final_kernel<<<(Nn + 255) / 256, 256, 0, stream>>>(outp, h2d, dinv, b2, out);
}

// Round 7
// 120.990 us; speedup vs baseline: 5.0550x; 1.2228x over previous
//
#include <hip/hip_runtime.h>

#define Nn 100000
#define Ee 1600000
#define HID 128
#define IN_DIM 5
#define N5 (Nn * IN_DIM)

// ---- bucket geometry: 1024 nodes/bucket, 98 buckets ----
#define SH2 10
#define BSZ2 1024
#define NB2 98
#define BCAP 18432        // expect ~16327, sigma ~128 -> +16 sigma headroom

#define PCHUNK 2000       // edges per partition block
#define PBLK (Ee / PCHUNK)   // 800 blocks

#define CPB1 8            // chunks/bucket for scalar passes (deg, out2)
#define CPB2 12           // chunks/bucket for 5-float pass (pre1) -> grid 1176

// ---------- kernel 1: one-pass radix partition of the edge list ----------
// rec = (d_local << 17) | src   (src < 2^17, d_local < 2^10)
__global__ __launch_bounds__(512) void partition_kernel(const int* __restrict__ src,
                                                        const int* __restrict__ dst,
                                                        unsigned int* __restrict__ recs,
                                                        int* __restrict__ bcnt) {
    __shared__ unsigned int stage[PCHUNK];   // 8 KB
    __shared__ int hist[NB2 + 1];
    __shared__ int cur[NB2];
    __shared__ int gbase[NB2];
    int e0 = blockIdx.x * PCHUNK;
    if (threadIdx.x <= NB2) hist[threadIdx.x] = 0;
    __syncthreads();
    for (int e = e0 + threadIdx.x; e < e0 + PCHUNK; e += 512)
        atomicAdd(&hist[(dst[e] >> SH2) + 1], 1);
    __syncthreads();
    if (threadIdx.x == 0)
        for (int b = 1; b <= NB2; ++b) hist[b] += hist[b - 1];
    __syncthreads();
    if (threadIdx.x < NB2) {
        int c0 = hist[threadIdx.x], c1 = hist[threadIdx.x + 1];
        cur[threadIdx.x] = c0;
        gbase[threadIdx.x] = atomicAdd(&bcnt[threadIdx.x], c1 - c0);
    }
    __syncthreads();
    for (int e = e0 + threadIdx.x; e < e0 + PCHUNK; e += 512) {
        int d = dst[e], s = src[e];
        int b = d >> SH2;
        int slot = atomicAdd(&cur[b], 1);
        stage[slot] = ((unsigned int)(d & (BSZ2 - 1)) << 17) | (unsigned int)s;
    }
    __syncthreads();
    int wave = threadIdx.x >> 6, lane = threadIdx.x & 63;
    for (int b = wave; b < NB2; b += 8) {
        int c0 = hist[b], len = hist[b + 1] - c0;
        unsigned int* o = recs + (size_t)b * BCAP + gbase[b];
        for (int i = lane; i < len; i += 64) o[i] = stage[c0 + i];
    }
}

// ---------- kernel 2: per-bucket in-degree from records (ILP-4) ----------
__global__ __launch_bounds__(512) void degbin2_kernel(const unsigned int* __restrict__ recs,
                                                      const int* __restrict__ bcnt,
                                                      float* __restrict__ degp) {
    __shared__ int acc[BSZ2];                // 4 KB
    int b = blockIdx.x / CPB1, c = blockIdx.x % CPB1;
    int n = bcnt[b];
    int r0 = (int)((long long)n * c / CPB1), r1 = (int)((long long)n * (c + 1) / CPB1);
    for (int i = threadIdx.x; i < BSZ2; i += 512) acc[i] = 0;
    __syncthreads();
    const unsigned int* R = recs + (size_t)b * BCAP;
    int i = r0 + (int)threadIdx.x;
    for (; i + 3 * 512 < r1; i += 4 * 512) {
        unsigned int ra = R[i], rb = R[i + 512], rc = R[i + 1024], rd = R[i + 1536];
        atomicAdd(&acc[ra >> 17], 1);
        atomicAdd(&acc[rb >> 17], 1);
        atomicAdd(&acc[rc >> 17], 1);
        atomicAdd(&acc[rd >> 17], 1);
    }
    for (; i < r1; i += 512) atomicAdd(&acc[R[i] >> 17], 1);
    __syncthreads();
    int base = b << SH2;
    int cnt = min(BSZ2, Nn - base);
    float* o = degp + (size_t)c * Nn + base;
    for (int j = threadIdx.x; j < cnt; j += 512) o[j] = (float)acc[j];
}

// ---------- kernel 3: dinv = rsqrt(deg+1); xd8 = x*dinv (8-float padded rows) ----------
__global__ void prep_kernel(const float* __restrict__ x, const float* __restrict__ degp,
                            float* __restrict__ dinv, float* __restrict__ xd8) {
    int i = blockIdx.x * blockDim.x + threadIdx.x;
    if (i < Nn) {
        float dg = 1.0f;
        #pragma unroll
        for (int c = 0; c < CPB1; ++c) dg += degp[(size_t)c * Nn + i];
        float di = rsqrtf(dg);
        dinv[i] = di;
        #pragma unroll
        for (int k = 0; k < IN_DIM; ++k)
            xd8[(size_t)i * 8 + k] = x[i * IN_DIM + k] * di;
    }
}

// ---------- kernel 4: layer-1 input aggregation from records (ILP-4) ----------
__global__ __launch_bounds__(512) void pre1bin2_kernel(const unsigned int* __restrict__ recs,
                                                       const int* __restrict__ bcnt,
                                                       const float* __restrict__ xd8,
                                                       float* __restrict__ pre1p) {
    __shared__ float acc[BSZ2 * IN_DIM];     // 20 KB
    int b = blockIdx.x / CPB2, c = blockIdx.x % CPB2;
    int n = bcnt[b];
    int r0 = (int)((long long)n * c / CPB2), r1 = (int)((long long)n * (c + 1) / CPB2);
    float4* accv = (float4*)acc;
    for (int i = threadIdx.x; i < BSZ2 * IN_DIM / 4; i += 512)
        accv[i] = make_float4(0.f, 0.f, 0.f, 0.f);
    __syncthreads();
    const unsigned int* R = recs + (size_t)b * BCAP;
    int i = r0 + (int)threadIdx.x;
    for (; i + 3 * 512 < r1; i += 4 * 512) {
        unsigned int r[4] = {R[i], R[i + 512], R[i + 1024], R[i + 1536]};
        float4 v[4]; float w[4];
        #pragma unroll
        for (int q = 0; q < 4; ++q) {
            int s = (int)(r[q] & 0x1FFFFu);
            v[q] = *(const float4*)&xd8[(size_t)s * 8];
            w[q] = xd8[(size_t)s * 8 + 4];
        }
        #pragma unroll
        for (int q = 0; q < 4; ++q) {
            int dl = (int)(r[q] >> 17) * IN_DIM;
            atomicAdd(&acc[dl + 0], v[q].x);
            atomicAdd(&acc[dl + 1], v[q].y);
            atomicAdd(&acc[dl + 2], v[q].z);
            atomicAdd(&acc[dl + 3], v[q].w);
            atomicAdd(&acc[dl + 4], w[q]);
        }
    }
    for (; i < r1; i += 512) {
        unsigned int ra = R[i];
        int s = (int)(ra & 0x1FFFFu);
        float4 va = *(const float4*)&xd8[(size_t)s * 8];
        float  wa = xd8[(size_t)s * 8 + 4];
        int dl = (int)(ra >> 17) * IN_DIM;
        atomicAdd(&acc[dl + 0], va.x);
        atomicAdd(&acc[dl + 1], va.y);
        atomicAdd(&acc[dl + 2], va.z);
        atomicAdd(&acc[dl + 3], va.w);
        atomicAdd(&acc[dl + 4], wa);
    }
    __syncthreads();
    int base = b << SH2;
    int cnt4 = min(BSZ2, Nn - base) * IN_DIM / 4;
    float4* o = (float4*)(pre1p + (size_t)c * N5 + (size_t)base * IN_DIM);
    for (int j = threadIdx.x; j < cnt4; j += 512) o[j] = accv[j];
}

// ---------- kernel 5: fused partial-reduce + layer-1 finish + ReLU + layer-2 proj ----------
// thread-per-node: sum CPB2 partials, apply dinv, W1 (LDS), ReLU, W2 (LDS)
__global__ __launch_bounds__(256) void node1_kernel(const float* __restrict__ pre1p,
                             const float* __restrict__ xd8,
                             const float* __restrict__ W1, const float* __restrict__ b1,
                             const float* __restrict__ W2, const float* __restrict__ dinv,
                             float* __restrict__ h2d) {
    __shared__ float w1s[IN_DIM * HID];      // 2.5 KB
    __shared__ float w2s[HID], b1s[HID];
    int tid = threadIdx.x;
    for (int j = tid; j < IN_DIM * HID; j += 256) w1s[j] = W1[j];
    if (tid < HID) { w2s[tid] = W2[tid]; b1s[tid] = b1[tid]; }
    __syncthreads();
    int nnode = blockIdx.x * 256 + tid;
    if (nnode >= Nn) return;
    float a5[IN_DIM] = {0.f, 0.f, 0.f, 0.f, 0.f};
    #pragma unroll
    for (int c = 0; c < CPB2; ++c) {
        const float* p = pre1p + (size_t)c * N5 + (size_t)nnode * IN_DIM;
        #pragma unroll
        for (int k = 0; k < IN_DIM; ++k) a5[k] += p[k];
    }
    float di = dinv[nnode];
    #pragma unroll
    for (int k = 0; k < IN_DIM; ++k)
        a5[k] = (a5[k] + xd8[(size_t)nnode * 8 + k]) * di;  // neighbor + self-loop, x coef
    float accp = 0.f;
    #pragma unroll
    for (int f = 0; f < HID; ++f) {
        float v = b1s[f];
        #pragma unroll
        for (int k = 0; k < IN_DIM; ++k) v += a5[k] * w1s[k * HID + f];
        v = fmaxf(v, 0.f);
        accp += v * w2s[f];
    }
    h2d[nnode] = accp * di;
}

// ---------- kernel 6: layer-2 scalar aggregation from records (ILP-4) ----------
__global__ __launch_bounds__(512) void out2bin2_kernel(const unsigned int* __restrict__ recs,
                                                       const int* __restrict__ bcnt,
                                                       const float* __restrict__ h2d,
                                                       float* __restrict__ outp) {
    __shared__ float acc[BSZ2];              // 4 KB
    int b = blockIdx.x / CPB1, c = blockIdx.x % CPB1;
    int n = bcnt[b];
    int r0 = (int)((long long)n * c / CPB1), r1 = (int)((long long)n * (c + 1) / CPB1);
    for (int i = threadIdx.x; i < BSZ2; i += 512) acc[i] = 0.f;
    __syncthreads();
    const unsigned int* R = recs + (size_t)b * BCAP;
    int i = r0 + (int)threadIdx.x;
    for (; i + 3 * 512 < r1; i += 4 * 512) {
        unsigned int ra = R[i], rb = R[i + 512], rc = R[i + 1024], rd = R[i + 1536];
        float ha = h2d[ra & 0x1FFFFu];
        float hb = h2d[rb & 0x1FFFFu];
        float hc = h2d[rc & 0x1FFFFu];
        float hd = h2d[rd & 0x1FFFFu];
        atomicAdd(&acc[ra >> 17], ha);
        atomicAdd(&acc[rb >> 17], hb);
        atomicAdd(&acc[rc >> 17], hc);
        atomicAdd(&acc[rd >> 17], hd);
    }
    for (; i < r1; i += 512) {
        unsigned int ra = R[i];
        atomicAdd(&acc[ra >> 17], h2d[ra & 0x1FFFFu]);
    }
    __syncthreads();
    int base = b << SH2;
    int cnt = min(BSZ2, Nn - base);
    float* o = outp + (size_t)c * Nn + base;
    for (int j = threadIdx.x; j < cnt; j += 512) o[j] = acc[j];
}

// ---------- kernel 7: final reduce + self-loop + b2 ----------
__global__ void final_kernel(const float* __restrict__ outp, const float* __restrict__ h2d,
                             const float* __restrict__ dinv, const float* __restrict__ b2,
                             float* __restrict__ out) {
    int n = blockIdx.x * blockDim.x + threadIdx.x;
    if (n < Nn) {
        float v = 0.f;
        #pragma unroll
        for (int c = 0; c < CPB1; ++c) v += outp[(size_t)c * Nn + n];
        out[n] = (v + h2d[n]) * dinv[n] + b2[0];
    }
}

extern "C" void kernel_launch(void* const* d_in, const int* in_sizes, int n_in,
                              void* d_out, int out_size, void* d_ws, size_t ws_size,
                              hipStream_t stream) {
    const float* x  = (const float*)d_in[0];
    const int*   ei = (const int*)d_in[1];     // [2, E]: src row then dst row
    const float* W1 = (const float*)d_in[2];
    const float* b1 = (const float*)d_in[3];
    const float* W2 = (const float*)d_in[4];
    const float* b2 = (const float*)d_in[5];
    const int* src = ei;
    const int* dst = ei + Ee;

    float* dinv  = (float*)d_ws;                    // N
    float* xd8   = dinv + Nn;                       // N*8
    float* h2d   = xd8 + (size_t)Nn * 8;            // N
    float* degp  = h2d + Nn;                        // CPB1*N (reused as outp)
    float* pre1p = degp + (size_t)CPB1 * Nn;        // CPB2*N5 (24 MB)
    unsigned int* recs = (unsigned int*)(pre1p + (size_t)CPB2 * N5);  // NB2*BCAP (7.2 MB)
    int* bcnt = (int*)(recs + (size_t)NB2 * BCAP);  // NB2 ints
    float* outp = degp;                             // alias: deg consumed before layer 2
    float* out  = (float*)d_out;

    hipMemsetAsync(bcnt, 0, NB2 * sizeof(int), stream);

    partition_kernel<<<PBLK, 512, 0, stream>>>(src, dst, recs, bcnt);
    degbin2_kernel<<<NB2 * CPB1, 512, 0, stream>>>(recs, bcnt, degp);
    prep_kernel<<<(Nn + 255) / 256, 256, 0, stream>>>(x, degp, dinv, xd8);
    pre1bin2_kernel<<<NB2 * CPB2, 512, 0, stream>>>(recs, bcnt, xd8, pre1p);
    node1_kernel<<<(Nn + 255) / 256, 256, 0, stream>>>(pre1p, xd8, W1, b1, W2, dinv, h2d);
    out2bin2_kernel<<<NB2 * CPB1, 512, 0, stream>>>(recs, bcnt, h2d, outp);
    final_kernel<<<(Nn + 255) / 256, 256, 0, stream>>>(outp, h2d, dinv, b2, out);
}